// Round 12
// baseline (635.996 us; speedup 1.0000x reference)
//
#include <hip/hip_runtime.h>

// C51 distributional Q target, R12: PER-LAYER KERNEL SPLIT.
// kA: X->H1 (LN+SiLU), kB: H1->H2, kC: H2->H3, kD: H3->logits->softmax->
// C51 projection->out. Activations bf16 in d_ws (chunked if ws too small;
// monolithic R11 fallback if ws_size < ~30MB). Tiles move between kernels as
// LINEAR copies of the swizzled 32-row tile (coalesced memcpy both ways).
// Each kernel: 32 rows/block, 4 waves, proven gemm_rolled + in-reg LN path.

#define THREADS 256
#define PREP_THREADS 256

typedef __attribute__((ext_vector_type(8))) short short8v;
typedef __attribute__((ext_vector_type(4))) float f32x4;

__device__ __forceinline__ unsigned short f2bf(float f) {
  union { float f; unsigned u; } v; v.f = f;
  unsigned u = v.u;
  u += 0x7fffu + ((u >> 16) & 1u);   // RNE
  return (unsigned short)(u >> 16);
}
__device__ __forceinline__ unsigned pack2bf(float a, float b) {
  unsigned r;
  asm("v_cvt_pk_bf16_f32 %0, %1, %2" : "=v"(r) : "v"(a), "v"(b));
  return r;
}

// ---------------- prep: weights fp32 [K][N] -> bf16 [N][K] in ws -------------
__global__ void prep_kernel(const float* __restrict__ W1, const float* __restrict__ W2,
                            const float* __restrict__ W3, const float* __restrict__ W4,
                            unsigned short* __restrict__ ws) {
  int i = blockIdx.x * PREP_THREADS + threadIdx.x;
  if (i < 81920) {
    int n = i / 160, k = i - n * 160;
    ws[i] = f2bf(W1[k * 512 + n]);
  } else if (i < 212992) {
    int j = i - 81920; int n = j >> 9, k = j & 511;
    ws[i] = f2bf(W2[k * 256 + n]);
  } else if (i < 245760) {
    int j = i - 212992; int n = j >> 8, k = j & 255;
    ws[i] = f2bf(W3[k * 128 + n]);
  } else if (i < 278528) {
    int j = i - 245760; int n = j >> 7, k = j & 127;
    ws[i] = (n < 251) ? f2bf(W4[k * 251 + n]) : (unsigned short)0;
  }
}

// ---- rolled GEMM (R11-proven): acc[ft][rt] += WT[fbase+..][k]*H[rt*16+..][k]
template<int KD, int NFT>
__device__ __forceinline__ void gemm_rolled(const unsigned short* __restrict__ WT,
                                            const unsigned char* __restrict__ Hb,
                                            int fbase, f32x4 (&acc)[NFT][2]) {
  constexpr int KS = KD / 32;
  const int lane = threadIdx.x & 63;
  const int lm = lane & 15, kg = lane >> 4;
  const unsigned short* wp = WT + (fbase + lm) * KD + kg * 8;
  int bbase[2], bswz[2];
#pragma unroll
  for (int rt = 0; rt < 2; ++rt) {
    const int r = rt * 16 + lm;
    bbase[rt] = r * (KD * 2) + kg * 16;
    bswz[rt] = (r & 7) << 4;
  }
  short8v A0[NFT], A1[NFT], B0[2], B1[2];
  auto loadA = [&](short8v (&A)[NFT], int k) {
#pragma unroll
    for (int ft = 0; ft < NFT; ++ft)
      A[ft] = *(const short8v*)(wp + ft * (16 * KD) + k * 32);
  };
  auto loadB = [&](short8v (&B)[2], int k) {
#pragma unroll
    for (int rt = 0; rt < 2; ++rt)
      B[rt] = *(const short8v*)(Hb + ((bbase[rt] + k * 64) ^ bswz[rt]));
  };
  auto domfma = [&](short8v (&A)[NFT], short8v (&B)[2]) {
#pragma unroll
    for (int ft = 0; ft < NFT; ++ft) {
      acc[ft][0] = __builtin_amdgcn_mfma_f32_16x16x32_bf16(A[ft], B[0], acc[ft][0], 0, 0, 0);
      acc[ft][1] = __builtin_amdgcn_mfma_f32_16x16x32_bf16(A[ft], B[1], acc[ft][1], 0, 0, 0);
    }
  };
  loadA(A0, 0); loadB(B0, 0);
  if constexpr ((KS & 1) == 0) {
#pragma unroll 1
    for (int ks = 0; ks < KS - 2; ks += 2) {
      loadA(A1, ks + 1); loadB(B1, ks + 1);
      domfma(A0, B0);
      loadA(A0, ks + 2); loadB(B0, ks + 2);
      domfma(A1, B1);
    }
    loadA(A1, KS - 1); loadB(B1, KS - 1);
    domfma(A0, B0);
    domfma(A1, B1);
  } else {
#pragma unroll 1
    for (int ks = 0; ks < KS - 1; ks += 2) {
      loadA(A1, ks + 1); loadB(B1, ks + 1);
      domfma(A0, B0);
      loadA(A0, ks + 2); loadB(B0, ks + 2);
      domfma(A1, B1);
    }
    domfma(A0, B0);
  }
}

// ---- bias + LN + SiLU in regs -> packed b64 store to swizzled LDS [32][ND]
template<int ND, int NFT>
__device__ __forceinline__ void ln_silu_store(
    f32x4 (&acc)[NFT][2],
    const float* __restrict__ bias, const float* __restrict__ g,
    const float* __restrict__ be, unsigned char* __restrict__ Hb,
    float* __restrict__ redL, int fbase, int fq)
{
  const int lane = threadIdx.x & 63;
  const int lm = lane & 15, kg = lane >> 4;
  float s[2] = {0.f, 0.f}, q[2] = {0.f, 0.f};
#pragma unroll
  for (int ft = 0; ft < NFT; ++ft) {
    const int f0 = fbase + ft * 16 + kg * 4;
    const f32x4 bb = *(const f32x4*)(bias + f0);
#pragma unroll
    for (int rt = 0; rt < 2; ++rt)
#pragma unroll
      for (int rg = 0; rg < 4; ++rg) {
        float x = acc[ft][rt][rg] + bb[rg];
        acc[ft][rt][rg] = x;
        s[rt] += x; q[rt] += x * x;
      }
  }
#pragma unroll
  for (int rt = 0; rt < 2; ++rt) {
    s[rt] += __shfl_xor(s[rt], 16); s[rt] += __shfl_xor(s[rt], 32);
    q[rt] += __shfl_xor(q[rt], 16); q[rt] += __shfl_xor(q[rt], 32);
  }
  if (lane < 16) {
#pragma unroll
    for (int rt = 0; rt < 2; ++rt) {
      redL[(rt * 16 + lm) * 9 + fq * 2    ] = s[rt];
      redL[(rt * 16 + lm) * 9 + fq * 2 + 1] = q[rt];
    }
  }
  __syncthreads();
  float mean[2], rstd[2];
#pragma unroll
  for (int rt = 0; rt < 2; ++rt) {
    const int row = rt * 16 + lm;
    float S = 0.f, Q = 0.f;
#pragma unroll
    for (int w = 0; w < 4; ++w) {
      S += redL[row * 9 + w * 2];
      Q += redL[row * 9 + w * 2 + 1];
    }
    float m = S * (1.0f / ND);
    float v = Q * (1.0f / ND) - m * m;
    mean[rt] = m; rstd[rt] = rsqrtf(v + 1e-5f);
  }
#pragma unroll
  for (int ft = 0; ft < NFT; ++ft) {
    const int f0 = fbase + ft * 16 + kg * 4;
    const f32x4 g4 = *(const f32x4*)(g + f0);
    const f32x4 e4 = *(const f32x4*)(be + f0);
#pragma unroll
    for (int rt = 0; rt < 2; ++rt) {
      const int row = rt * 16 + lm;
      float h[4];
#pragma unroll
      for (int rg = 0; rg < 4; ++rg) {
        float y = (acc[ft][rt][rg] - mean[rt]) * rstd[rt] * g4[rg] + e4[rg];
        h[rg] = y * (1.0f / (1.0f + __expf(-y)));
      }
      uint2 w; w.x = pack2bf(h[0], h[1]); w.y = pack2bf(h[2], h[3]);
      int byte = row * (ND * 2) + f0 * 2;
      byte ^= ((row & 7) << 4);
      *(uint2*)(Hb + byte) = w;
    }
  }
}

// linear LDS<->global tile copies (tiles stored swizzled in global, 16B units)
template<int NU4>
__device__ __forceinline__ void tile_flush(const unsigned char* R, unsigned short* g) {
  const uint4* s = (const uint4*)R;
  uint4* d = (uint4*)g;
  for (int i = threadIdx.x; i < NU4; i += THREADS) d[i] = s[i];
}
template<int NU4>
__device__ __forceinline__ void tile_stage(unsigned char* R, const unsigned short* g) {
  const uint4* s = (const uint4*)g;
  uint4* d = (uint4*)R;
  for (int i = threadIdx.x; i < NU4; i += THREADS) d[i] = s[i];
}

// -------------------- kA: X -> H1 [32rows x 512] ----------------------------
__global__ __launch_bounds__(THREADS, 4) void kA(
    const float* __restrict__ obs, const float* __restrict__ actions,
    const float* __restrict__ b1, const float* __restrict__ g1,
    const float* __restrict__ be1, const unsigned short* __restrict__ ws,
    unsigned short* __restrict__ H1, int row_base)
{
  __shared__ __align__(16) unsigned char smem[32768 + 1152];
  unsigned char* R = smem;
  float* redL = (float*)(smem + 32768);
  const int tid = threadIdx.x, fq = tid >> 6;
  const int row0 = row_base + blockIdx.x * 32;

  // stage X bf16 [32][160] swizzled
#pragma unroll 1
  for (int it = 0; it < 5; ++it) {
    const int qq = it * THREADS + tid;
    const int r  = qq / 40;
    const int c4 = (qq - r * 40) * 4;
    float4 v;
    if (c4 < 128) v = *(const float4*)(obs + (size_t)(row0 + r) * 128 + c4);
    else          v = *(const float4*)(actions + (size_t)(row0 + r) * 32 + (c4 - 128));
    uint2 w; w.x = pack2bf(v.x, v.y); w.y = pack2bf(v.z, v.w);
    int byte = r * 320 + c4 * 2;
    byte ^= ((r & 7) << 4);
    *(uint2*)(R + byte) = w;
  }
  __syncthreads();

  f32x4 acc[8][2];
#pragma unroll
  for (int i = 0; i < 8; ++i) { acc[i][0] = f32x4{0,0,0,0}; acc[i][1] = f32x4{0,0,0,0}; }
  gemm_rolled<160, 8>(ws, R, fq * 128, acc);
  ln_silu_store<512, 8>(acc, b1, g1, be1, R, redL, fq * 128, fq);
  __syncthreads();
  tile_flush<2048>(R, H1 + (size_t)blockIdx.x * (32 * 512));
}

// -------------------- kB: H1 -> H2 [32 x 256] -------------------------------
__global__ __launch_bounds__(THREADS, 4) void kB(
    const float* __restrict__ b2, const float* __restrict__ g2,
    const float* __restrict__ be2, const unsigned short* __restrict__ ws,
    const unsigned short* __restrict__ H1, unsigned short* __restrict__ H2)
{
  __shared__ __align__(16) unsigned char smem[32768 + 1152];
  unsigned char* R = smem;
  float* redL = (float*)(smem + 32768);
  const int tid = threadIdx.x, fq = tid >> 6;
  tile_stage<2048>(R, H1 + (size_t)blockIdx.x * (32 * 512));
  __syncthreads();
  f32x4 acc[4][2];
#pragma unroll
  for (int i = 0; i < 4; ++i) { acc[i][0] = f32x4{0,0,0,0}; acc[i][1] = f32x4{0,0,0,0}; }
  gemm_rolled<512, 4>(ws + 81920, R, fq * 64, acc);
  ln_silu_store<256, 4>(acc, b2, g2, be2, R, redL, fq * 64, fq);
  __syncthreads();
  tile_flush<1024>(R, H2 + (size_t)blockIdx.x * (32 * 256));
}

// -------------------- kC: H2 -> H3 [32 x 128] -------------------------------
__global__ __launch_bounds__(THREADS, 4) void kC(
    const float* __restrict__ b3, const float* __restrict__ g3,
    const float* __restrict__ be3, const unsigned short* __restrict__ ws,
    const unsigned short* __restrict__ H2, unsigned short* __restrict__ H3)
{
  __shared__ __align__(16) unsigned char smem[16384 + 1152];
  unsigned char* R = smem;
  float* redL = (float*)(smem + 16384);
  const int tid = threadIdx.x, fq = tid >> 6;
  tile_stage<1024>(R, H2 + (size_t)blockIdx.x * (32 * 256));
  __syncthreads();
  f32x4 acc[2][2];
#pragma unroll
  for (int i = 0; i < 2; ++i) { acc[i][0] = f32x4{0,0,0,0}; acc[i][1] = f32x4{0,0,0,0}; }
  gemm_rolled<256, 2>(ws + 212992, R, fq * 32, acc);
  ln_silu_store<128, 2>(acc, b3, g3, be3, R, redL, fq * 32, fq);
  __syncthreads();
  tile_flush<512>(R, H3 + (size_t)blockIdx.x * (32 * 128));
}

// ------ kD: H3 -> logits -> softmax -> C51 projection -> out ----------------
__global__ __launch_bounds__(THREADS, 4) void kD(
    const float* __restrict__ rewards, const float* __restrict__ bootstrap,
    const float* __restrict__ discount, const float* __restrict__ q_support,
    const float* __restrict__ b4, const unsigned short* __restrict__ ws,
    const unsigned short* __restrict__ H3, float* __restrict__ out, int row_base)
{
  __shared__ __align__(16) unsigned char smem[32128 + 1024 + 1024 + 640];
  unsigned char* R = smem;                       // H3 tile (8KB) then proj
  float* zsL  = (float*)(smem + 32128);
  float* b4L  = (float*)(smem + 33152);
  float* redL = (float*)(smem + 34176);
  const int tid = threadIdx.x, fq = tid >> 6;
  const int lane = tid & 63, lm = lane & 15, kg = lane >> 4;
  const int row0 = row_base + blockIdx.x * 32;

  zsL[tid] = (tid < 251) ? q_support[tid] : 0.f;
  b4L[tid] = (tid < 251) ? b4[tid] : 0.f;
  tile_stage<512>(R, H3 + (size_t)blockIdx.x * (32 * 128));
  __syncthreads();

  f32x4 acc4[4][2];
#pragma unroll
  for (int i = 0; i < 4; ++i) { acc4[i][0] = f32x4{0,0,0,0}; acc4[i][1] = f32x4{0,0,0,0}; }
  gemm_rolled<128, 4>(ws + 245760, R, fq * 64, acc4);

  float rw[2], bt[2], dc[2];
#pragma unroll
  for (int rt = 0; rt < 2; ++rt) {
    const int r = row0 + rt * 16 + lm;
    rw[rt] = rewards[r]; bt[rt] = bootstrap[r]; dc[rt] = discount[r];
  }

  float lv[4][2][4];
#pragma unroll
  for (int ft = 0; ft < 4; ++ft) {
    const int f0 = fq * 64 + ft * 16 + kg * 4;
    const f32x4 bb = *(const f32x4*)(b4L + f0);
#pragma unroll
    for (int rt = 0; rt < 2; ++rt)
#pragma unroll
      for (int rg = 0; rg < 4; ++rg) {
        const int f = f0 + rg;
        lv[ft][rt][rg] = (f < 251) ? (acc4[ft][rt][rg] + bb[rg]) : -1e30f;
      }
  }

#pragma unroll
  for (int rt = 0; rt < 2; ++rt) {
    float m = lv[0][rt][0];
#pragma unroll
    for (int ft = 0; ft < 4; ++ft)
#pragma unroll
      for (int rg = 0; rg < 4; ++rg) m = fmaxf(m, lv[ft][rt][rg]);
    m = fmaxf(m, __shfl_xor(m, 16));
    m = fmaxf(m, __shfl_xor(m, 32));
    if (lane < 16) redL[(rt * 16 + lm) * 5 + fq] = m;
  }
  __syncthreads();   // all waves past H3 reads; redL max visible

  float* projL = (float*)R;   // overwrites H3 tile (dead)
  for (int i = tid; i < 32 * 251; i += THREADS) projL[i] = 0.f;

  float gm[2];
#pragma unroll
  for (int rt = 0; rt < 2; ++rt) {
    const int row = rt * 16 + lm;
    float m = redL[row * 5];
#pragma unroll
    for (int w = 1; w < 4; ++w) m = fmaxf(m, redL[row * 5 + w]);
    gm[rt] = m;
  }
  __syncthreads();
#pragma unroll
  for (int rt = 0; rt < 2; ++rt) {
    float E = 0.f;
#pragma unroll
    for (int ft = 0; ft < 4; ++ft)
#pragma unroll
      for (int rg = 0; rg < 4; ++rg) {
        float e = __expf(lv[ft][rt][rg] - gm[rt]);
        lv[ft][rt][rg] = e;
        E += e;
      }
    E += __shfl_xor(E, 16); E += __shfl_xor(E, 32);
    if (lane < 16) redL[(rt * 16 + lm) * 5 + fq] = E;
  }
  __syncthreads();
  float inv[2];
#pragma unroll
  for (int rt = 0; rt < 2; ++rt) {
    const int row = rt * 16 + lm;
    float E = 0.f;
#pragma unroll
    for (int w = 0; w < 4; ++w) E += redL[row * 5 + w];
    inv[rt] = 1.0f / E;
  }

  constexpr float DZF = 20.0f / 250.0f;
  constexpr float INVDZ = 1.0f / DZF;
#pragma unroll
  for (int ft = 0; ft < 4; ++ft) {
    const int f0 = fq * 64 + ft * 16 + kg * 4;
    const f32x4 z4 = *(const f32x4*)(zsL + f0);
#pragma unroll
    for (int rt = 0; rt < 2; ++rt) {
      const int base = (rt * 16 + lm) * 251;
      const float bd = __fmul_rn(bt[rt], dc[rt]);
#pragma unroll
      for (int rg = 0; rg < 4; ++rg) {
        const int f = f0 + rg;
        if (f < 251) {
          const float p = lv[ft][rt][rg] * inv[rt];
          float t = __fadd_rn(rw[rt], __fmul_rn(bd, z4[rg]));
          t = fminf(fmaxf(t, -10.0f), 10.0f);
          const float bfr = __fmul_rn(__fsub_rn(t, -10.0f), INVDZ);
          const float fl = floorf(bfr), fu = ceilf(bfr);
          int l = (int)fl, u = (int)fu;
          if (fl == fu) { if (l > 0) --l; else ++u; }
          atomicAdd(projL + base + l, p * ((float)u - bfr));
          atomicAdd(projL + base + u, p * (bfr - (float)l));
        }
      }
    }
  }
  __syncthreads();

  const float4* ps = (const float4*)projL;
  float4* po = (float4*)(out + (size_t)row0 * 251);
  for (int i = tid; i < 2008; i += THREADS) po[i] = ps[i];
}

// -------------------- monolithic fallback (R11, proven) ---------------------
#define OFF_R   0
#define OFF_ZS  32768
#define OFF_B4  33792
#define OFF_RED 34816
#define LDS_TOTAL 36096

__global__ __launch_bounds__(THREADS, 4) void fused_kernel(
    const float* __restrict__ obs, const float* __restrict__ actions,
    const float* __restrict__ rewards, const float* __restrict__ bootstrap,
    const float* __restrict__ discount, const float* __restrict__ q_support,
    const float* __restrict__ b1, const float* __restrict__ g1, const float* __restrict__ be1,
    const float* __restrict__ b2, const float* __restrict__ g2, const float* __restrict__ be2,
    const float* __restrict__ b3, const float* __restrict__ g3, const float* __restrict__ be3,
    const float* __restrict__ b4,
    const unsigned short* __restrict__ ws,
    float* __restrict__ out)
{
  __shared__ __align__(16) unsigned char smem[LDS_TOTAL];
  const int tid  = threadIdx.x;
  const int fq   = tid >> 6;
  const int lane = tid & 63;
  const int lm   = lane & 15;
  const int kg   = lane >> 4;
  const int row0 = blockIdx.x * 32;

  const unsigned short* W1T = ws;
  const unsigned short* W2T = ws + 81920;
  const unsigned short* W3T = ws + 212992;
  const unsigned short* W4T = ws + 245760;

  float* zsL  = (float*)(smem + OFF_ZS);
  float* b4L  = (float*)(smem + OFF_B4);
  float* redL = (float*)(smem + OFF_RED);

  float rw[2], bt[2], dc[2];
#pragma unroll
  for (int rt = 0; rt < 2; ++rt) {
    const int r = row0 + rt * 16 + lm;
    rw[rt] = rewards[r]; bt[rt] = bootstrap[r]; dc[rt] = discount[r];
  }
  zsL[tid] = (tid < 251) ? q_support[tid] : 0.f;
  b4L[tid] = (tid < 251) ? b4[tid] : 0.f;

  {
    unsigned char* Xb = smem + OFF_R;
#pragma unroll 1
    for (int it = 0; it < 5; ++it) {
      const int qq = it * THREADS + tid;
      const int r  = qq / 40;
      const int c4 = (qq - r * 40) * 4;
      float4 v;
      if (c4 < 128) v = *(const float4*)(obs + (size_t)(row0 + r) * 128 + c4);
      else          v = *(const float4*)(actions + (size_t)(row0 + r) * 32 + (c4 - 128));
      uint2 w; w.x = pack2bf(v.x, v.y); w.y = pack2bf(v.z, v.w);
      int byte = r * 320 + c4 * 2;
      byte ^= ((r & 7) << 4);
      *(uint2*)(Xb + byte) = w;
    }
  }
  __syncthreads();

  f32x4 acc1[8][2];
#pragma unroll
  for (int i = 0; i < 8; ++i) { acc1[i][0] = f32x4{0,0,0,0}; acc1[i][1] = f32x4{0,0,0,0}; }
  gemm_rolled<160, 8>(W1T, smem + OFF_R, fq * 128, acc1);
  ln_silu_store<512, 8>(acc1, b1, g1, be1, smem + OFF_R, redL, fq * 128, fq);
  __syncthreads();

  f32x4 acc2[4][2];
#pragma unroll
  for (int i = 0; i < 4; ++i) { acc2[i][0] = f32x4{0,0,0,0}; acc2[i][1] = f32x4{0,0,0,0}; }
  gemm_rolled<512, 4>(W2T, smem + OFF_R, fq * 64, acc2);
  ln_silu_store<256, 4>(acc2, b2, g2, be2, smem + OFF_R, redL, fq * 64, fq);
  __syncthreads();

  f32x4 acc3[2][2];
#pragma unroll
  for (int i = 0; i < 2; ++i) { acc3[i][0] = f32x4{0,0,0,0}; acc3[i][1] = f32x4{0,0,0,0}; }
  gemm_rolled<256, 2>(W3T, smem + OFF_R, fq * 32, acc3);
  ln_silu_store<128, 2>(acc3, b3, g3, be3, smem + OFF_R, redL, fq * 32, fq);
  __syncthreads();

  f32x4 acc4[4][2];
#pragma unroll
  for (int i = 0; i < 4; ++i) { acc4[i][0] = f32x4{0,0,0,0}; acc4[i][1] = f32x4{0,0,0,0}; }
  gemm_rolled<128, 4>(W4T, smem + OFF_R, fq * 64, acc4);

  float lv[4][2][4];
#pragma unroll
  for (int ft = 0; ft < 4; ++ft) {
    const int f0 = fq * 64 + ft * 16 + kg * 4;
    const f32x4 bb = *(const f32x4*)(b4L + f0);
#pragma unroll
    for (int rt = 0; rt < 2; ++rt)
#pragma unroll
      for (int rg = 0; rg < 4; ++rg) {
        const int f = f0 + rg;
        lv[ft][rt][rg] = (f < 251) ? (acc4[ft][rt][rg] + bb[rg]) : -1e30f;
      }
  }

#pragma unroll
  for (int rt = 0; rt < 2; ++rt) {
    float m = lv[0][rt][0];
#pragma unroll
    for (int ft = 0; ft < 4; ++ft)
#pragma unroll
      for (int rg = 0; rg < 4; ++rg) m = fmaxf(m, lv[ft][rt][rg]);
    m = fmaxf(m, __shfl_xor(m, 16));
    m = fmaxf(m, __shfl_xor(m, 32));
    if (lane < 16) redL[(rt * 16 + lm) * 5 + fq] = m;
  }
  __syncthreads();

  float* projL = (float*)(smem + OFF_R);
  for (int i = tid; i < 32 * 251; i += THREADS) projL[i] = 0.f;

  float gm[2];
#pragma unroll
  for (int rt = 0; rt < 2; ++rt) {
    const int row = rt * 16 + lm;
    float m = redL[row * 5];
#pragma unroll
    for (int w = 1; w < 4; ++w) m = fmaxf(m, redL[row * 5 + w]);
    gm[rt] = m;
  }
  __syncthreads();
#pragma unroll
  for (int rt = 0; rt < 2; ++rt) {
    float E = 0.f;
#pragma unroll
    for (int ft = 0; ft < 4; ++ft)
#pragma unroll
      for (int rg = 0; rg < 4; ++rg) {
        float e = __expf(lv[ft][rt][rg] - gm[rt]);
        lv[ft][rt][rg] = e;
        E += e;
      }
    E += __shfl_xor(E, 16); E += __shfl_xor(E, 32);
    if (lane < 16) redL[(rt * 16 + lm) * 5 + fq] = E;
  }
  __syncthreads();
  float inv[2];
#pragma unroll
  for (int rt = 0; rt < 2; ++rt) {
    const int row = rt * 16 + lm;
    float E = 0.f;
#pragma unroll
    for (int w = 0; w < 4; ++w) E += redL[row * 5 + w];
    inv[rt] = 1.0f / E;
  }

  constexpr float DZF = 20.0f / 250.0f;
  constexpr float INVDZ = 1.0f / DZF;
#pragma unroll
  for (int ft = 0; ft < 4; ++ft) {
    const int f0 = fq * 64 + ft * 16 + kg * 4;
    const f32x4 z4 = *(const f32x4*)(zsL + f0);
#pragma unroll
    for (int rt = 0; rt < 2; ++rt) {
      const int base = (rt * 16 + lm) * 251;
      const float bd = __fmul_rn(bt[rt], dc[rt]);
#pragma unroll
      for (int rg = 0; rg < 4; ++rg) {
        const int f = f0 + rg;
        if (f < 251) {
          const float p = lv[ft][rt][rg] * inv[rt];
          float t = __fadd_rn(rw[rt], __fmul_rn(bd, z4[rg]));
          t = fminf(fmaxf(t, -10.0f), 10.0f);
          const float bfr = __fmul_rn(__fsub_rn(t, -10.0f), INVDZ);
          const float fl = floorf(bfr), fu = ceilf(bfr);
          int l = (int)fl, u = (int)fu;
          if (fl == fu) { if (l > 0) --l; else ++u; }
          atomicAdd(projL + base + l, p * ((float)u - bfr));
          atomicAdd(projL + base + u, p * (bfr - (float)l));
        }
      }
    }
  }
  __syncthreads();

  const float4* ps = (const float4*)projL;
  float4* po = (float4*)(out + (size_t)row0 * 251);
  for (int i = tid; i < 2008; i += THREADS) po[i] = ps[i];
}

extern "C" void kernel_launch(void* const* d_in, const int* in_sizes, int n_in,
                              void* d_out, int out_size, void* d_ws, size_t ws_size,
                              hipStream_t stream) {
  const float* obs  = (const float*)d_in[0];
  const float* act  = (const float*)d_in[1];
  const float* rew  = (const float*)d_in[2];
  const float* boot = (const float*)d_in[3];
  const float* disc = (const float*)d_in[4];
  const float* zs   = (const float*)d_in[5];
  const float* W1   = (const float*)d_in[6];
  const float* b1   = (const float*)d_in[7];
  const float* g1   = (const float*)d_in[8];
  const float* be1  = (const float*)d_in[9];
  const float* W2   = (const float*)d_in[10];
  const float* b2   = (const float*)d_in[11];
  const float* g2   = (const float*)d_in[12];
  const float* be2  = (const float*)d_in[13];
  const float* W3   = (const float*)d_in[14];
  const float* b3   = (const float*)d_in[15];
  const float* g3   = (const float*)d_in[16];
  const float* be3  = (const float*)d_in[17];
  const float* W4   = (const float*)d_in[18];
  const float* b4   = (const float*)d_in[19];
  unsigned short* wsp = (unsigned short*)d_ws;

  const int Bn = in_sizes[2];          // batch = 131072
  prep_kernel<<<(278528 + PREP_THREADS - 1) / PREP_THREADS, PREP_THREADS, 0, stream>>>(
      W1, W2, W3, W4, wsp);

  // activation scratch requirement: 1792 B/row beyond the 557056-byte weights
  long long rcap = ((long long)ws_size - 557056LL - 4096LL) / 1792LL;
  long long Rc = rcap < 0 ? 0 : rcap;
  if (Rc > Bn) Rc = Bn;
  Rc &= ~31LL;

  if (Rc >= 16384) {
    unsigned short* H1 = wsp + 278528;
    unsigned short* H2 = H1 + (size_t)Rc * 512;
    unsigned short* H3 = H2 + (size_t)Rc * 256;
    for (int base = 0; base < Bn; base += (int)Rc) {
      const int rows = (Bn - base < (int)Rc) ? (Bn - base) : (int)Rc;
      const int nb = rows / 32;
      kA<<<nb, THREADS, 0, stream>>>(obs, act, b1, g1, be1, wsp, H1, base);
      kB<<<nb, THREADS, 0, stream>>>(b2, g2, be2, wsp, H1, H2);
      kC<<<nb, THREADS, 0, stream>>>(b3, g3, be3, wsp, H2, H3);
      kD<<<nb, THREADS, 0, stream>>>(rew, boot, disc, zs, b4, wsp, H3,
                                     (float*)d_out, base);
    }
  } else {
    fused_kernel<<<Bn / 32, THREADS, 0, stream>>>(obs, act, rew, boot, disc, zs,
        b1, g1, be1, b2, g2, be2, b3, g3, be3, b4, wsp, (float*)d_out);
  }
}

// Round 13
// 483.197 us; speedup vs baseline: 1.3162x; 1.3162x over previous
//
#include <hip/hip_runtime.h>

// C51 distributional Q target, R13 = R11 monolithic base (32 rows/block,
// 4 waves, operand-swapped MFMA, rolled K-loops, in-register LN/SiLU/softmax,
// 36KB time-muxed LDS, 4 blocks/CU) + ONE change: the C51 projection scatter
// uses unsafeAtomicAdd (native ds_add_f32) instead of atomicAdd (which
// lowers to a ds_cmpst CAS retry loop without -munsafe-fp-atomics).
// R12's per-layer split localized ~270us of anomalous time in the scatter.

#define THREADS 256
#define PREP_THREADS 256

typedef __attribute__((ext_vector_type(8))) short short8v;
typedef __attribute__((ext_vector_type(4))) float f32x4;

__device__ __forceinline__ unsigned short f2bf(float f) {
  union { float f; unsigned u; } v; v.f = f;
  unsigned u = v.u;
  u += 0x7fffu + ((u >> 16) & 1u);   // RNE
  return (unsigned short)(u >> 16);
}
// HW packed fp32->bf16 (RNE), 1 VALU inst for 2 values
__device__ __forceinline__ unsigned pack2bf(float a, float b) {
  unsigned r;
  asm("v_cvt_pk_bf16_f32 %0, %1, %2" : "=v"(r) : "v"(a), "v"(b));
  return r;
}
// native LDS fp32 atomic add (ds_add_f32), bypassing the CAS-loop lowering
__device__ __forceinline__ void lds_fadd(float* p, float v) {
  unsafeAtomicAdd(p, v);
}

// ---------------- prep: weights fp32 [K][N] -> bf16 [N][K] in ws -------------
// W1T @0 (512x160), W2T @81920 (256x512), W3T @212992 (128x256),
// W4T @245760 (256x128, rows n>=251 zero-padded)
__global__ void prep_kernel(const float* __restrict__ W1, const float* __restrict__ W2,
                            const float* __restrict__ W3, const float* __restrict__ W4,
                            unsigned short* __restrict__ ws) {
  int i = blockIdx.x * PREP_THREADS + threadIdx.x;
  if (i < 81920) {
    int n = i / 160, k = i - n * 160;
    ws[i] = f2bf(W1[k * 512 + n]);
  } else if (i < 212992) {
    int j = i - 81920; int n = j >> 9, k = j & 511;
    ws[i] = f2bf(W2[k * 256 + n]);
  } else if (i < 245760) {
    int j = i - 212992; int n = j >> 8, k = j & 255;
    ws[i] = f2bf(W3[k * 128 + n]);
  } else if (i < 278528) {
    int j = i - 245760; int n = j >> 7, k = j & 127;
    ws[i] = (n < 251) ? f2bf(W4[k * 251 + n]) : (unsigned short)0;
  }
}

// LDS layout (bytes). ONE time-multiplexed 32KB region R @0:
//   X bf16 [32][160] swz -> H1 [32][512] swz -> H2 [32][256] swz ->
//   H3 [32][128] swz -> proj f32 [32][251]
// Every overwrite is fenced by the LN reduction's internal __syncthreads.
#define OFF_R   0
#define OFF_ZS  32768
#define OFF_B4  33792
#define OFF_RED 34816
#define LDS_TOTAL 36096

// GEMM: acc[ft][rt] += WT[fbase+ft*16+..][k] * H[rt*16+..][k]
// MFMA 16x16x32 bf16, A = weight rows (m=feature), B = act rows (n=batch row).
// D: lane&15 = batch row in tile, (lane>>4)*4+reg = feature in tile.
// ROLLED ks-loop (#pragma unroll 1), ping-pong A0/A1,B0/B1 (static names),
// depth-2 software pipeline. acc[] indices remain compile-time (ft unrolled).
template<int KD, int NFT>
__device__ __forceinline__ void gemm_rolled(const unsigned short* __restrict__ WT,
                                            const unsigned char* __restrict__ Hb,
                                            int fbase, f32x4 (&acc)[NFT][2]) {
  constexpr int KS = KD / 32;
  const int lane = threadIdx.x & 63;
  const int lm = lane & 15, kg = lane >> 4;
  const unsigned short* wp = WT + (fbase + lm) * KD + kg * 8;
  int bbase[2], bswz[2];
#pragma unroll
  for (int rt = 0; rt < 2; ++rt) {
    const int r = rt * 16 + lm;
    bbase[rt] = r * (KD * 2) + kg * 16;
    bswz[rt] = (r & 7) << 4;
  }
  short8v A0[NFT], A1[NFT], B0[2], B1[2];

  auto loadA = [&](short8v (&A)[NFT], int k) {
#pragma unroll
    for (int ft = 0; ft < NFT; ++ft)
      A[ft] = *(const short8v*)(wp + ft * (16 * KD) + k * 32);
  };
  auto loadB = [&](short8v (&B)[2], int k) {
#pragma unroll
    for (int rt = 0; rt < 2; ++rt)
      B[rt] = *(const short8v*)(Hb + ((bbase[rt] + k * 64) ^ bswz[rt]));
  };
  auto domfma = [&](short8v (&A)[NFT], short8v (&B)[2]) {
#pragma unroll
    for (int ft = 0; ft < NFT; ++ft) {
      acc[ft][0] = __builtin_amdgcn_mfma_f32_16x16x32_bf16(A[ft], B[0], acc[ft][0], 0, 0, 0);
      acc[ft][1] = __builtin_amdgcn_mfma_f32_16x16x32_bf16(A[ft], B[1], acc[ft][1], 0, 0, 0);
    }
  };

  loadA(A0, 0); loadB(B0, 0);
  if constexpr ((KS & 1) == 0) {
#pragma unroll 1
    for (int ks = 0; ks < KS - 2; ks += 2) {
      loadA(A1, ks + 1); loadB(B1, ks + 1);
      domfma(A0, B0);
      loadA(A0, ks + 2); loadB(B0, ks + 2);
      domfma(A1, B1);
    }
    loadA(A1, KS - 1); loadB(B1, KS - 1);
    domfma(A0, B0);
    domfma(A1, B1);
  } else {
#pragma unroll 1
    for (int ks = 0; ks < KS - 1; ks += 2) {
      loadA(A1, ks + 1); loadB(B1, ks + 1);
      domfma(A0, B0);
      loadA(A0, ks + 2); loadB(B0, ks + 2);
      domfma(A1, B1);
    }
    domfma(A0, B0);   // ks = KS-1 already resident in A0/B0
  }
}

// bias + LayerNorm + SiLU entirely in registers, then one packed b64 store
// per (ft, rt) into swizzled LDS [32][ND] bf16. 4 waves reduce via redL
// (stride 9). Internal barrier doubles as the region-reuse fence.
template<int ND, int NFT>
__device__ __forceinline__ void ln_silu_store(
    f32x4 (&acc)[NFT][2],
    const float* __restrict__ bias, const float* __restrict__ g,
    const float* __restrict__ be, unsigned char* __restrict__ Hb,
    float* __restrict__ redL, int fbase, int fq)
{
  const int lane = threadIdx.x & 63;
  const int lm = lane & 15, kg = lane >> 4;
  float s[2] = {0.f, 0.f}, q[2] = {0.f, 0.f};
#pragma unroll
  for (int ft = 0; ft < NFT; ++ft) {
    const int f0 = fbase + ft * 16 + kg * 4;
    const f32x4 bb = *(const f32x4*)(bias + f0);
#pragma unroll
    for (int rt = 0; rt < 2; ++rt)
#pragma unroll
      for (int rg = 0; rg < 4; ++rg) {
        float x = acc[ft][rt][rg] + bb[rg];
        acc[ft][rt][rg] = x;
        s[rt] += x; q[rt] += x * x;
      }
  }
#pragma unroll
  for (int rt = 0; rt < 2; ++rt) {
    s[rt] += __shfl_xor(s[rt], 16); s[rt] += __shfl_xor(s[rt], 32);
    q[rt] += __shfl_xor(q[rt], 16); q[rt] += __shfl_xor(q[rt], 32);
  }
  if (lane < 16) {
#pragma unroll
    for (int rt = 0; rt < 2; ++rt) {
      redL[(rt * 16 + lm) * 9 + fq * 2    ] = s[rt];
      redL[(rt * 16 + lm) * 9 + fq * 2 + 1] = q[rt];
    }
  }
  __syncthreads();
  float mean[2], rstd[2];
#pragma unroll
  for (int rt = 0; rt < 2; ++rt) {
    const int row = rt * 16 + lm;
    float S = 0.f, Q = 0.f;
#pragma unroll
    for (int w = 0; w < 4; ++w) {
      S += redL[row * 9 + w * 2];
      Q += redL[row * 9 + w * 2 + 1];
    }
    float m = S * (1.0f / ND);
    float v = Q * (1.0f / ND) - m * m;
    mean[rt] = m; rstd[rt] = rsqrtf(v + 1e-5f);
  }
#pragma unroll
  for (int ft = 0; ft < NFT; ++ft) {
    const int f0 = fbase + ft * 16 + kg * 4;
    const f32x4 g4 = *(const f32x4*)(g + f0);
    const f32x4 e4 = *(const f32x4*)(be + f0);
#pragma unroll
    for (int rt = 0; rt < 2; ++rt) {
      const int row = rt * 16 + lm;
      float h[4];
#pragma unroll
      for (int rg = 0; rg < 4; ++rg) {
        float y = (acc[ft][rt][rg] - mean[rt]) * rstd[rt] * g4[rg] + e4[rg];
        h[rg] = y * (1.0f / (1.0f + __expf(-y)));
      }
      uint2 w; w.x = pack2bf(h[0], h[1]); w.y = pack2bf(h[2], h[3]);
      int byte = row * (ND * 2) + f0 * 2;
      byte ^= ((row & 7) << 4);
      *(uint2*)(Hb + byte) = w;
    }
  }
}

__global__ __launch_bounds__(THREADS, 4) void fused_kernel(
    const float* __restrict__ obs, const float* __restrict__ actions,
    const float* __restrict__ rewards, const float* __restrict__ bootstrap,
    const float* __restrict__ discount, const float* __restrict__ q_support,
    const float* __restrict__ b1, const float* __restrict__ g1, const float* __restrict__ be1,
    const float* __restrict__ b2, const float* __restrict__ g2, const float* __restrict__ be2,
    const float* __restrict__ b3, const float* __restrict__ g3, const float* __restrict__ be3,
    const float* __restrict__ b4,
    const unsigned short* __restrict__ ws,
    float* __restrict__ out)
{
  __shared__ __align__(16) unsigned char smem[LDS_TOTAL];
  const int tid  = threadIdx.x;
  const int fq   = tid >> 6;          // wave = feature-quarter, 0..3
  const int lane = tid & 63;
  const int lm   = lane & 15;
  const int kg   = lane >> 4;
  const int row0 = blockIdx.x * 32;

  const unsigned short* W1T = ws;
  const unsigned short* W2T = ws + 81920;
  const unsigned short* W3T = ws + 212992;
  const unsigned short* W4T = ws + 245760;

  float* zsL  = (float*)(smem + OFF_ZS);
  float* b4L  = (float*)(smem + OFF_B4);
  float* redL = (float*)(smem + OFF_RED);

  // per-row scalars straight to registers (each lane owns rows rt*16+lm)
  float rw[2], bt[2], dc[2];
#pragma unroll
  for (int rt = 0; rt < 2; ++rt) {
    const int r = row0 + rt * 16 + lm;
    rw[rt] = rewards[r]; bt[rt] = bootstrap[r]; dc[rt] = discount[r];
  }

  // stage q_support / b4 (padded to 256, avoids OOB vector loads)
  zsL[tid] = (tid < 251) ? q_support[tid] : 0.f;
  b4L[tid] = (tid < 251) ? b4[tid] : 0.f;

  // stage X = concat(obs, actions) bf16 [32][160], swizzled (1280 uint2)
  {
    unsigned char* Xb = smem + OFF_R;
#pragma unroll 1
    for (int it = 0; it < 5; ++it) {
      const int qq = it * THREADS + tid;     // 0..1279, 40 float4 per row
      const int r  = qq / 40;
      const int c4 = (qq - r * 40) * 4;
      float4 v;
      if (c4 < 128) v = *(const float4*)(obs + (size_t)(row0 + r) * 128 + c4);
      else          v = *(const float4*)(actions + (size_t)(row0 + r) * 32 + (c4 - 128));
      uint2 w; w.x = pack2bf(v.x, v.y); w.y = pack2bf(v.z, v.w);
      int byte = r * 320 + c4 * 2;
      byte ^= ((r & 7) << 4);
      *(uint2*)(Xb + byte) = w;
    }
  }
  __syncthreads();

  // ---- layer 1: 512 feats, K=160; 128 feats/wave ----
  f32x4 acc1[8][2];
#pragma unroll
  for (int i = 0; i < 8; ++i) { acc1[i][0] = f32x4{0,0,0,0}; acc1[i][1] = f32x4{0,0,0,0}; }
  gemm_rolled<160, 8>(W1T, smem + OFF_R, fq * 128, acc1);
  ln_silu_store<512, 8>(acc1, b1, g1, be1, smem + OFF_R, redL, fq * 128, fq);
  __syncthreads();

  // ---- layer 2: 256 feats, K=512; 64 feats/wave ----
  f32x4 acc2[4][2];
#pragma unroll
  for (int i = 0; i < 4; ++i) { acc2[i][0] = f32x4{0,0,0,0}; acc2[i][1] = f32x4{0,0,0,0}; }
  gemm_rolled<512, 4>(W2T, smem + OFF_R, fq * 64, acc2);
  ln_silu_store<256, 4>(acc2, b2, g2, be2, smem + OFF_R, redL, fq * 64, fq);
  __syncthreads();

  // ---- layer 3: 128 feats, K=256; 32 feats/wave ----
  f32x4 acc3[2][2];
#pragma unroll
  for (int i = 0; i < 2; ++i) { acc3[i][0] = f32x4{0,0,0,0}; acc3[i][1] = f32x4{0,0,0,0}; }
  gemm_rolled<256, 2>(W3T, smem + OFF_R, fq * 32, acc3);
  ln_silu_store<128, 2>(acc3, b3, g3, be3, smem + OFF_R, redL, fq * 32, fq);
  __syncthreads();

  // ---- layer 4: logits, 256pad feats, K=128; 64 feats/wave ----
  f32x4 acc4[4][2];
#pragma unroll
  for (int i = 0; i < 4; ++i) { acc4[i][0] = f32x4{0,0,0,0}; acc4[i][1] = f32x4{0,0,0,0}; }
  gemm_rolled<128, 4>(W4T, smem + OFF_R, fq * 64, acc4);

  float lv[4][2][4];
#pragma unroll
  for (int ft = 0; ft < 4; ++ft) {
    const int f0 = fq * 64 + ft * 16 + kg * 4;
    const f32x4 bb = *(const f32x4*)(b4L + f0);
#pragma unroll
    for (int rt = 0; rt < 2; ++rt)
#pragma unroll
      for (int rg = 0; rg < 4; ++rg) {
        const int f = f0 + rg;
        lv[ft][rt][rg] = (f < 251) ? (acc4[ft][rt][rg] + bb[rg]) : -1e30f;
      }
  }

  // ---- softmax over 251 features per row (stride-5 padded reduction) ----
#pragma unroll
  for (int rt = 0; rt < 2; ++rt) {
    float m = lv[0][rt][0];
#pragma unroll
    for (int ft = 0; ft < 4; ++ft)
#pragma unroll
      for (int rg = 0; rg < 4; ++rg) m = fmaxf(m, lv[ft][rt][rg]);
    m = fmaxf(m, __shfl_xor(m, 16));
    m = fmaxf(m, __shfl_xor(m, 32));
    if (lane < 16) redL[(rt * 16 + lm) * 5 + fq] = m;
  }
  __syncthreads();   // all waves past GEMM4's H3 reads; redL max visible

  // zero proj buffer (region R; overwrites H3 — dead now)
  float* projL = (float*)(smem + OFF_R);
  for (int i = tid; i < 32 * 251; i += THREADS) projL[i] = 0.f;

  float gm[2];
#pragma unroll
  for (int rt = 0; rt < 2; ++rt) {
    const int row = rt * 16 + lm;
    float m = redL[row * 5];
#pragma unroll
    for (int w = 1; w < 4; ++w) m = fmaxf(m, redL[row * 5 + w]);
    gm[rt] = m;
  }
  __syncthreads();   // redL reuse + proj zeros visible
#pragma unroll
  for (int rt = 0; rt < 2; ++rt) {
    float E = 0.f;
#pragma unroll
    for (int ft = 0; ft < 4; ++ft)
#pragma unroll
      for (int rg = 0; rg < 4; ++rg) {
        float e = __expf(lv[ft][rt][rg] - gm[rt]);
        lv[ft][rt][rg] = e;
        E += e;
      }
    E += __shfl_xor(E, 16); E += __shfl_xor(E, 32);
    if (lane < 16) redL[(rt * 16 + lm) * 5 + fq] = E;
  }
  __syncthreads();
  float inv[2];
#pragma unroll
  for (int rt = 0; rt < 2; ++rt) {
    const int row = rt * 16 + lm;
    float E = 0.f;
#pragma unroll
    for (int w = 0; w < 4; ++w) E += redL[row * 5 + w];
    inv[rt] = 1.0f / E;
  }

  // ---- C51 projection scatter (native ds_add_f32 atomics) ----
  // b = (t+10)*(1/DZ): <=1ulp off the correctly-rounded divide; the two-point
  // interpolation is continuous in b, so output error is O(1e-7).
  constexpr float DZF = 20.0f / 250.0f;
  constexpr float INVDZ = 1.0f / DZF;
#pragma unroll
  for (int ft = 0; ft < 4; ++ft) {
    const int f0 = fq * 64 + ft * 16 + kg * 4;
    const f32x4 z4 = *(const f32x4*)(zsL + f0);
#pragma unroll
    for (int rt = 0; rt < 2; ++rt) {
      const int base = (rt * 16 + lm) * 251;
      const float bd = __fmul_rn(bt[rt], dc[rt]);
#pragma unroll
      for (int rg = 0; rg < 4; ++rg) {
        const int f = f0 + rg;
        if (f < 251) {
          const float p = lv[ft][rt][rg] * inv[rt];
          float t = __fadd_rn(rw[rt], __fmul_rn(bd, z4[rg]));
          t = fminf(fmaxf(t, -10.0f), 10.0f);
          const float bfr = __fmul_rn(__fsub_rn(t, -10.0f), INVDZ);
          const float fl = floorf(bfr), fu = ceilf(bfr);
          int l = (int)fl, u = (int)fu;
          if (fl == fu) { if (l > 0) --l; else ++u; }
          lds_fadd(projL + base + l, p * ((float)u - bfr));
          lds_fadd(projL + base + u, p * (bfr - (float)l));
        }
      }
    }
  }
  __syncthreads();

  // ---- write out: block slice contiguous (32*251 floats = 2008 float4) ----
  const float4* ps = (const float4*)projL;
  float4* po = (float4*)(out + (size_t)row0 * 251);
  for (int i = tid; i < 2008; i += THREADS) po[i] = ps[i];
}

extern "C" void kernel_launch(void* const* d_in, const int* in_sizes, int n_in,
                              void* d_out, int out_size, void* d_ws, size_t ws_size,
                              hipStream_t stream) {
  const float* obs  = (const float*)d_in[0];
  const float* act  = (const float*)d_in[1];
  const float* rew  = (const float*)d_in[2];
  const float* boot = (const float*)d_in[3];
  const float* disc = (const float*)d_in[4];
  const float* zs   = (const float*)d_in[5];
  const float* W1   = (const float*)d_in[6];
  const float* b1   = (const float*)d_in[7];
  const float* g1   = (const float*)d_in[8];
  const float* be1  = (const float*)d_in[9];
  const float* W2   = (const float*)d_in[10];
  const float* b2   = (const float*)d_in[11];
  const float* g2   = (const float*)d_in[12];
  const float* be2  = (const float*)d_in[13];
  const float* W3   = (const float*)d_in[14];
  const float* b3   = (const float*)d_in[15];
  const float* g3   = (const float*)d_in[16];
  const float* be3  = (const float*)d_in[17];
  const float* W4   = (const float*)d_in[18];
  const float* b4   = (const float*)d_in[19];
  unsigned short* wsp = (unsigned short*)d_ws;

  const int Bn = in_sizes[2];          // batch = 131072
  prep_kernel<<<(278528 + PREP_THREADS - 1) / PREP_THREADS, PREP_THREADS, 0, stream>>>(
      W1, W2, W3, W4, wsp);
  fused_kernel<<<Bn / 32, THREADS, 0, stream>>>(obs, act, rew, boot, disc, zs,
      b1, g1, be1, b2, g2, be2, b3, g3, be3, b4, wsp, (float*)d_out);
}